// Round 1
// baseline (2095.083 us; speedup 1.0000x reference)
//
#include <hip/hip_runtime.h>
#include <math.h>

#define N_ATOMS   50000
#define N_BONDS   500000
#define N_TRIPLES 2000000
#define DD        64

// ---------------------------------------------------------------------------
// Kernel A: upd[a,c] = sigmoid(atom[a,:] @ W_update[:,c] + b_update[c])
// 4 atoms per 256-thread block; W (16KB) staged in LDS; rows staged in LDS.
// ---------------------------------------------------------------------------
__global__ __launch_bounds__(256) void atom_update_kernel(
    const float* __restrict__ atom, const float* __restrict__ W,
    const float* __restrict__ b, float* __restrict__ out)
{
    __shared__ float sW[DD * DD];
    __shared__ float sRow[4 * DD];
    for (int i = threadIdx.x; i < DD * DD; i += 256) sW[i] = W[i];
    size_t base = (size_t)blockIdx.x * (4 * DD);
    sRow[threadIdx.x] = atom[base + threadIdx.x];
    __syncthreads();

    int local = threadIdx.x >> 6;   // which of the 4 atoms
    int c     = threadIdx.x & 63;   // output channel
    float sum = b[c];
#pragma unroll
    for (int k = 0; k < DD; ++k)
        sum = fmaf(sRow[local * DD + k], sW[k * DD + c], sum);
    out[base + threadIdx.x] = 1.0f / (1.0f + __expf(-sum));
}

// ---------------------------------------------------------------------------
// Kernel B: per triple t:
//   dst  = tbi[t,0]; src = tbi[t,1]; a = bai[src,1]
//   summed[dst,:] += basis[t,:] * upd[a,:]        (f32 atomics)
// 16 triples per 256-thread block; 16 threads/triple, 4 channels/thread
// (float4 loads). upd table is 12.8MB -> L2/L3 resident.
// ---------------------------------------------------------------------------
__global__ __launch_bounds__(256) void scatter_kernel(
    const float* __restrict__ basis, const float* __restrict__ upd,
    const int* __restrict__ tbi, const int* __restrict__ bai,
    float* __restrict__ summed)
{
    int t  = blockIdx.x * 16 + (threadIdx.x >> 4);
    int c0 = (threadIdx.x & 15) * 4;

    int dst = tbi[2 * t];
    int src = tbi[2 * t + 1];
    int a   = bai[2 * src + 1];

    const float4 bs = *reinterpret_cast<const float4*>(basis + (size_t)t * DD + c0);
    const float4 uu = *reinterpret_cast<const float4*>(upd   + (size_t)a * DD + c0);

    float* p = summed + (size_t)dst * DD + c0;
    atomicAdd(p + 0, bs.x * uu.x);
    atomicAdd(p + 1, bs.y * uu.y);
    atomicAdd(p + 2, bs.z * uu.z);
    atomicAdd(p + 3, bs.w * uu.w);
}

// ---------------------------------------------------------------------------
// Kernel C (in-place on io == d_out holding summed_messages):
//   io[bond,c] = bond_features[bond,c] + (io[bond,:] @ W_fuse[:,c]) + b_fuse[c]
// Safe in place: each block stages its 4 rows into LDS, syncs, then writes.
// ---------------------------------------------------------------------------
__global__ __launch_bounds__(256) void fuse_kernel(
    const float* __restrict__ bond, const float* __restrict__ W,
    const float* __restrict__ b, float* __restrict__ io)
{
    __shared__ float sW[DD * DD];
    __shared__ float sRow[4 * DD];
    for (int i = threadIdx.x; i < DD * DD; i += 256) sW[i] = W[i];
    size_t base = (size_t)blockIdx.x * (4 * DD);
    sRow[threadIdx.x] = io[base + threadIdx.x];
    __syncthreads();

    int local = threadIdx.x >> 6;
    int c     = threadIdx.x & 63;
    float sum = b[c];
#pragma unroll
    for (int k = 0; k < DD; ++k)
        sum = fmaf(sRow[local * DD + k], sW[k * DD + c], sum);
    io[base + threadIdx.x] = bond[base + threadIdx.x] + sum;
}

extern "C" void kernel_launch(void* const* d_in, const int* in_sizes, int n_in,
                              void* d_out, int out_size, void* d_ws, size_t ws_size,
                              hipStream_t stream) {
    const float* atom  = (const float*)d_in[0];  // (50000, 64)
    const float* bond  = (const float*)d_in[1];  // (500000, 64)
    const float* basis = (const float*)d_in[2];  // (2000000, 64)
    const int*   bai   = (const int*)d_in[3];    // (500000, 2)
    const int*   tbi   = (const int*)d_in[4];    // (2000000, 2)
    const float* Wu    = (const float*)d_in[5];  // (64, 64)
    const float* bu    = (const float*)d_in[6];  // (64,)
    const float* Wf    = (const float*)d_in[7];  // (64, 64)
    const float* bf    = (const float*)d_in[8];  // (64,)

    float* out = (float*)d_out;                  // (500000, 64) — also the segment-sum accumulator
    float* upd = (float*)d_ws;                   // (50000, 64) = 12.8 MB scratch

    // 1) zero the segment-sum accumulator (graph-capture-safe async memset)
    hipMemsetAsync(out, 0, (size_t)N_BONDS * DD * sizeof(float), stream);

    // 2) per-atom update: sigmoid(atom @ W_update + b_update)
    atom_update_kernel<<<N_ATOMS / 4, 256, 0, stream>>>(atom, Wu, bu, upd);

    // 3) gather + multiply + segment-sum (atomics into d_out)
    scatter_kernel<<<N_TRIPLES / 16, 256, 0, stream>>>(basis, upd, tbi, bai, out);

    // 4) fuse: out = bond_features + summed @ W_fuse + b_fuse (in place)
    fuse_kernel<<<N_BONDS / 4, 256, 0, stream>>>(bond, Wf, bf, out);
}

// Round 2
// 1020.388 us; speedup vs baseline: 2.0532x; 2.0532x over previous
//
#include <hip/hip_runtime.h>
#include <math.h>

#define N_ATOMS   50000
#define N_BONDS   500000
#define N_TRIPLES 2000000
#define DD        64

// ---------------- workspace layout (bytes, all 256-aligned) ----------------
#define O_UPD   0u                          // 50000*64*4 = 12,800,000
#define O_CNT   12800000u                   // 500000*4 -> pad 2,000,128
#define O_OFF   (O_CNT + 2000128u)
#define O_CUR   (O_OFF + 2000128u)
#define O_BS    (O_CUR + 2000128u)          // block sums (245 ints, pad 4096)
#define O_PAIRS (O_BS + 4096u)              // 2,000,000 * 8 = 16,000,000
#define WS_NEED ((size_t)O_PAIRS + (size_t)N_TRIPLES * 8u)

#define SCAN_ELEMS 2048
#define SCAN_NBLK  ((N_BONDS + SCAN_ELEMS - 1) / SCAN_ELEMS)   // 245

// ---------------------------------------------------------------------------
// A: upd[a,c] = sigmoid(atom[a,:] @ W_update[:,c] + b_update[c])
// ---------------------------------------------------------------------------
__global__ __launch_bounds__(256) void atom_update_kernel(
    const float* __restrict__ atom, const float* __restrict__ W,
    const float* __restrict__ b, float* __restrict__ out)
{
    __shared__ float sW[DD * DD];
    __shared__ float sRow[4 * DD];
    for (int i = threadIdx.x; i < DD * DD; i += 256) sW[i] = W[i];
    size_t base = (size_t)blockIdx.x * (4 * DD);
    sRow[threadIdx.x] = atom[base + threadIdx.x];
    __syncthreads();

    int local = threadIdx.x >> 6;
    int c     = threadIdx.x & 63;
    float sum = b[c];
#pragma unroll
    for (int k = 0; k < DD; ++k)
        sum = fmaf(sRow[local * DD + k], sW[k * DD + c], sum);
    out[base + threadIdx.x] = 1.0f / (1.0f + __expf(-sum));
}

// ---------------------------------------------------------------------------
// B1: counts[dst]++ per triple
// ---------------------------------------------------------------------------
__global__ __launch_bounds__(256) void count_kernel(
    const int* __restrict__ tbi, int* __restrict__ counts)
{
    int t = blockIdx.x * 256 + threadIdx.x;
    if (t < N_TRIPLES) atomicAdd(&counts[tbi[2 * t]], 1);
}

// ---------------------------------------------------------------------------
// B2a: per-block exclusive scan (2048 elems/block) + block sums
// ---------------------------------------------------------------------------
__global__ __launch_bounds__(256) void scan_blocks_kernel(
    const int* __restrict__ counts, int* __restrict__ offsets,
    int* __restrict__ blockSums)
{
    __shared__ int s[256];
    int base = blockIdx.x * SCAN_ELEMS + threadIdx.x * 8;
    int v[8];
    int tsum = 0;
#pragma unroll
    for (int i = 0; i < 8; ++i) {
        int idx = base + i;
        v[i] = (idx < N_BONDS) ? counts[idx] : 0;
        tsum += v[i];
    }
    s[threadIdx.x] = tsum;
    __syncthreads();
    // Hillis-Steele inclusive scan over 256 thread sums
    for (int off = 1; off < 256; off <<= 1) {
        int x = 0;
        if (threadIdx.x >= off) x = s[threadIdx.x - off];
        __syncthreads();
        if (threadIdx.x >= off) s[threadIdx.x] += x;
        __syncthreads();
    }
    int excl = s[threadIdx.x] - tsum;
    if (threadIdx.x == 255) blockSums[blockIdx.x] = s[255];
    int run = excl;
#pragma unroll
    for (int i = 0; i < 8; ++i) {
        int idx = base + i;
        if (idx < N_BONDS) offsets[idx] = run;
        run += v[i];
    }
}

// ---------------------------------------------------------------------------
// B2b: exclusive scan of the 245 block sums (single block, LDS serial)
// ---------------------------------------------------------------------------
__global__ __launch_bounds__(256) void scan_top_kernel(int* __restrict__ blockSums)
{
    __shared__ int s[SCAN_NBLK];
    for (int i = threadIdx.x; i < SCAN_NBLK; i += 256) s[i] = blockSums[i];
    __syncthreads();
    if (threadIdx.x == 0) {
        int acc = 0;
        for (int i = 0; i < SCAN_NBLK; ++i) { int t = s[i]; s[i] = acc; acc += t; }
    }
    __syncthreads();
    for (int i = threadIdx.x; i < SCAN_NBLK; i += 256) blockSums[i] = s[i];
}

// ---------------------------------------------------------------------------
// B2c: offsets += scanned block sum; cursor = offsets
// ---------------------------------------------------------------------------
__global__ __launch_bounds__(256) void add_offsets_kernel(
    int* __restrict__ offsets, const int* __restrict__ blockSums,
    int* __restrict__ cursor)
{
    int i = blockIdx.x * 256 + threadIdx.x;
    if (i < N_BONDS) {
        int o = offsets[i] + blockSums[i / SCAN_ELEMS];
        offsets[i] = o;
        cursor[i]  = o;
    }
}

// ---------------------------------------------------------------------------
// B3: fill CSR pairs[slot] = (triple_idx, atom_idx)
// ---------------------------------------------------------------------------
__global__ __launch_bounds__(256) void fill_kernel(
    const int* __restrict__ tbi, const int* __restrict__ bai,
    int* __restrict__ cursor, int2* __restrict__ pairs)
{
    int t = blockIdx.x * 256 + threadIdx.x;
    if (t >= N_TRIPLES) return;
    int dst = tbi[2 * t];
    int src = tbi[2 * t + 1];
    int a   = bai[2 * src + 1];
    int slot = atomicAdd(&cursor[dst], 1);
    pairs[slot] = make_int2(t, a);
}

// ---------------------------------------------------------------------------
// D: gather + segment-sum in registers + fused (@W_fuse + b_fuse + bond)
// One wave (64 lanes) per bond; 4 bonds per 256-thread block.
// ---------------------------------------------------------------------------
__global__ __launch_bounds__(256) void gather_fuse_kernel(
    const float* __restrict__ basis, const float* __restrict__ upd,
    const int2* __restrict__ pairs, const int* __restrict__ offsets,
    const int* __restrict__ counts, const float* __restrict__ bond,
    const float* __restrict__ W, const float* __restrict__ b,
    float* __restrict__ out)
{
    __shared__ float sW[DD * DD];
    __shared__ float sRow[4 * DD];
    for (int i = threadIdx.x; i < DD * DD; i += 256) sW[i] = W[i];

    int wave = threadIdx.x >> 6;
    int c    = threadIdx.x & 63;
    int bnd  = blockIdx.x * 4 + wave;

    int off = offsets[bnd];
    int cnt = counts[bnd];

    float acc = 0.0f;
    for (int j = off; j < off + cnt; ++j) {
        int2 p = pairs[j];                       // wave-uniform address
        acc += basis[(size_t)p.x * DD + c] * upd[(size_t)p.y * DD + c];
    }
    sRow[threadIdx.x] = acc;
    __syncthreads();

    float sum = b[c];
#pragma unroll
    for (int k = 0; k < DD; ++k)
        sum = fmaf(sRow[wave * DD + k], sW[k * DD + c], sum);

    size_t o = (size_t)bnd * DD + c;
    out[o] = bond[o] + sum;
}

// ---------------------------------------------------------------------------
// Fallback path (ws too small): round-1 atomic scatter
// ---------------------------------------------------------------------------
__global__ __launch_bounds__(256) void scatter_kernel(
    const float* __restrict__ basis, const float* __restrict__ upd,
    const int* __restrict__ tbi, const int* __restrict__ bai,
    float* __restrict__ summed)
{
    int t  = blockIdx.x * 16 + (threadIdx.x >> 4);
    int c0 = (threadIdx.x & 15) * 4;
    int dst = tbi[2 * t];
    int src = tbi[2 * t + 1];
    int a   = bai[2 * src + 1];
    const float4 bs = *reinterpret_cast<const float4*>(basis + (size_t)t * DD + c0);
    const float4 uu = *reinterpret_cast<const float4*>(upd   + (size_t)a * DD + c0);
    float* p = summed + (size_t)dst * DD + c0;
    atomicAdd(p + 0, bs.x * uu.x);
    atomicAdd(p + 1, bs.y * uu.y);
    atomicAdd(p + 2, bs.z * uu.z);
    atomicAdd(p + 3, bs.w * uu.w);
}

__global__ __launch_bounds__(256) void fuse_kernel(
    const float* __restrict__ bond, const float* __restrict__ W,
    const float* __restrict__ b, float* __restrict__ io)
{
    __shared__ float sW[DD * DD];
    __shared__ float sRow[4 * DD];
    for (int i = threadIdx.x; i < DD * DD; i += 256) sW[i] = W[i];
    size_t base = (size_t)blockIdx.x * (4 * DD);
    sRow[threadIdx.x] = io[base + threadIdx.x];
    __syncthreads();
    int local = threadIdx.x >> 6;
    int c     = threadIdx.x & 63;
    float sum = b[c];
#pragma unroll
    for (int k = 0; k < DD; ++k)
        sum = fmaf(sRow[local * DD + k], sW[k * DD + c], sum);
    io[base + threadIdx.x] = bond[base + threadIdx.x] + sum;
}

extern "C" void kernel_launch(void* const* d_in, const int* in_sizes, int n_in,
                              void* d_out, int out_size, void* d_ws, size_t ws_size,
                              hipStream_t stream) {
    const float* atom  = (const float*)d_in[0];
    const float* bond  = (const float*)d_in[1];
    const float* basis = (const float*)d_in[2];
    const int*   bai   = (const int*)d_in[3];
    const int*   tbi   = (const int*)d_in[4];
    const float* Wu    = (const float*)d_in[5];
    const float* bu    = (const float*)d_in[6];
    const float* Wf    = (const float*)d_in[7];
    const float* bf    = (const float*)d_in[8];

    float* out = (float*)d_out;
    char*  ws  = (char*)d_ws;

    float* upd     = (float*)(ws + O_UPD);
    int*   counts  = (int*)  (ws + O_CNT);
    int*   offsets = (int*)  (ws + O_OFF);
    int*   cursor  = (int*)  (ws + O_CUR);
    int*   bsum    = (int*)  (ws + O_BS);
    int2*  pairs   = (int2*) (ws + O_PAIRS);

    // per-atom update table (both paths need it)
    atom_update_kernel<<<N_ATOMS / 4, 256, 0, stream>>>(atom, Wu, bu, upd);

    if (ws_size >= WS_NEED) {
        // ---- CSR build ----
        hipMemsetAsync(counts, 0, (size_t)N_BONDS * sizeof(int), stream);
        count_kernel<<<(N_TRIPLES + 255) / 256, 256, 0, stream>>>(tbi, counts);
        scan_blocks_kernel<<<SCAN_NBLK, 256, 0, stream>>>(counts, offsets, bsum);
        scan_top_kernel<<<1, 256, 0, stream>>>(bsum);
        add_offsets_kernel<<<(N_BONDS + 255) / 256, 256, 0, stream>>>(offsets, bsum, cursor);
        fill_kernel<<<(N_TRIPLES + 255) / 256, 256, 0, stream>>>(tbi, bai, cursor, pairs);

        // ---- gather + segment-sum + fused epilogue, single pass over out ----
        gather_fuse_kernel<<<N_BONDS / 4, 256, 0, stream>>>(
            basis, upd, pairs, offsets, counts, bond, Wf, bf, out);
    } else {
        // ---- fallback: atomic scatter (round-1 path) ----
        hipMemsetAsync(out, 0, (size_t)N_BONDS * DD * sizeof(float), stream);
        scatter_kernel<<<N_TRIPLES / 16, 256, 0, stream>>>(basis, upd, tbi, bai, out);
        fuse_kernel<<<N_BONDS / 4, 256, 0, stream>>>(bond, Wf, bf, out);
    }
}

// Round 3
// 699.494 us; speedup vs baseline: 2.9951x; 1.4588x over previous
//
#include <hip/hip_runtime.h>
#include <math.h>

#define N_ATOMS   50000
#define N_BONDS   500000
#define N_TRIPLES 2000000
#define DD        64

typedef float f4v __attribute__((ext_vector_type(4)));

// ---------------- workspace layout (bytes, all 256-aligned) ----------------
#define O_UPD   0u                          // 50000*64*4 = 12,800,000
#define O_CNT   12800000u                   // 500000*4 -> pad 2,000,128
#define O_OFF   (O_CNT + 2000128u)
#define O_CUR   (O_OFF + 2000128u)
#define O_BS    (O_CUR + 2000128u)          // block sums (245 ints, pad 4096)
#define O_PAIRS (O_BS + 4096u)              // 2,000,000 * 8 = 16,000,000
#define WS_NEED ((size_t)O_PAIRS + (size_t)N_TRIPLES * 8u)

#define SCAN_ELEMS 2048
#define SCAN_NBLK  ((N_BONDS + SCAN_ELEMS - 1) / SCAN_ELEMS)   // 245

// ---------------------------------------------------------------------------
// A: upd[a,c] = sigmoid(atom[a,:] @ W_update[:,c] + b_update[c])
// ---------------------------------------------------------------------------
__global__ __launch_bounds__(256) void atom_update_kernel(
    const float* __restrict__ atom, const float* __restrict__ W,
    const float* __restrict__ b, float* __restrict__ out)
{
    __shared__ float sW[DD * DD];
    __shared__ float sRow[4 * DD];
    for (int i = threadIdx.x; i < DD * DD; i += 256) sW[i] = W[i];
    size_t base = (size_t)blockIdx.x * (4 * DD);
    sRow[threadIdx.x] = atom[base + threadIdx.x];
    __syncthreads();

    int local = threadIdx.x >> 6;
    int c     = threadIdx.x & 63;
    float sum = b[c];
#pragma unroll
    for (int k = 0; k < DD; ++k)
        sum = fmaf(sRow[local * DD + k], sW[k * DD + c], sum);
    out[base + threadIdx.x] = 1.0f / (1.0f + __expf(-sum));
}

// ---------------------------------------------------------------------------
// B1: counts[dst]++ per triple
// ---------------------------------------------------------------------------
__global__ __launch_bounds__(256) void count_kernel(
    const int* __restrict__ tbi, int* __restrict__ counts)
{
    int t = blockIdx.x * 256 + threadIdx.x;
    if (t < N_TRIPLES) atomicAdd(&counts[tbi[2 * t]], 1);
}

// ---------------------------------------------------------------------------
// B2a: per-block exclusive scan (2048 elems/block) + block sums
// ---------------------------------------------------------------------------
__global__ __launch_bounds__(256) void scan_blocks_kernel(
    const int* __restrict__ counts, int* __restrict__ offsets,
    int* __restrict__ blockSums)
{
    __shared__ int s[256];
    int base = blockIdx.x * SCAN_ELEMS + threadIdx.x * 8;
    int v[8];
    int tsum = 0;
#pragma unroll
    for (int i = 0; i < 8; ++i) {
        int idx = base + i;
        v[i] = (idx < N_BONDS) ? counts[idx] : 0;
        tsum += v[i];
    }
    s[threadIdx.x] = tsum;
    __syncthreads();
    for (int off = 1; off < 256; off <<= 1) {
        int x = 0;
        if (threadIdx.x >= off) x = s[threadIdx.x - off];
        __syncthreads();
        if (threadIdx.x >= off) s[threadIdx.x] += x;
        __syncthreads();
    }
    int excl = s[threadIdx.x] - tsum;
    if (threadIdx.x == 255) blockSums[blockIdx.x] = s[255];
    int run = excl;
#pragma unroll
    for (int i = 0; i < 8; ++i) {
        int idx = base + i;
        if (idx < N_BONDS) offsets[idx] = run;
        run += v[i];
    }
}

// ---------------------------------------------------------------------------
// B2b: exclusive scan of the 245 block sums
// ---------------------------------------------------------------------------
__global__ __launch_bounds__(256) void scan_top_kernel(int* __restrict__ blockSums)
{
    __shared__ int s[SCAN_NBLK];
    for (int i = threadIdx.x; i < SCAN_NBLK; i += 256) s[i] = blockSums[i];
    __syncthreads();
    if (threadIdx.x == 0) {
        int acc = 0;
        for (int i = 0; i < SCAN_NBLK; ++i) { int t = s[i]; s[i] = acc; acc += t; }
    }
    __syncthreads();
    for (int i = threadIdx.x; i < SCAN_NBLK; i += 256) blockSums[i] = s[i];
}

// ---------------------------------------------------------------------------
// B2c: offsets += scanned block sum; cursor = offsets
// ---------------------------------------------------------------------------
__global__ __launch_bounds__(256) void add_offsets_kernel(
    int* __restrict__ offsets, const int* __restrict__ blockSums,
    int* __restrict__ cursor)
{
    int i = blockIdx.x * 256 + threadIdx.x;
    if (i < N_BONDS) {
        int o = offsets[i] + blockSums[i / SCAN_ELEMS];
        offsets[i] = o;
        cursor[i]  = o;
    }
}

// ---------------------------------------------------------------------------
// B3: fill CSR pairs[slot] = (triple_idx, atom_idx)
// ---------------------------------------------------------------------------
__global__ __launch_bounds__(256) void fill_kernel(
    const int* __restrict__ tbi, const int* __restrict__ bai,
    int* __restrict__ cursor, int2* __restrict__ pairs)
{
    int t = blockIdx.x * 256 + threadIdx.x;
    if (t >= N_TRIPLES) return;
    int dst = tbi[2 * t];
    int src = tbi[2 * t + 1];
    int a   = bai[2 * src + 1];
    int slot = atomicAdd(&cursor[dst], 1);
    pairs[slot] = make_int2(t, a);
}

// ---------------------------------------------------------------------------
// D: gather + segment-sum + fused (@W_fuse + b_fuse + bond_features)
// One wave per bond, remapped 4x16: each 16-lane group owns one triple
// (float4/lane covers all 64 channels) -> 4 triples in flight, 16B loads.
// ---------------------------------------------------------------------------
__global__ __launch_bounds__(256) void gather_fuse_kernel(
    const float* __restrict__ basis, const float* __restrict__ upd,
    const int2* __restrict__ pairs, const int* __restrict__ offsets,
    const int* __restrict__ counts, const float* __restrict__ bond,
    const float* __restrict__ W, const float* __restrict__ b,
    float* __restrict__ out)
{
    __shared__ float sW[DD * DD];
    __shared__ float sRow[4 * DD];
    for (int i = threadIdx.x; i < DD * DD; i += 256) sW[i] = W[i];

    int wave = threadIdx.x >> 6;
    int lane = threadIdx.x & 63;
    int g    = lane >> 4;          // triple group 0..3
    int c4   = (lane & 15) * 4;    // channel base for float4
    int bnd  = blockIdx.x * 4 + wave;

    int off = offsets[bnd];
    int cnt = counts[bnd];

    f4v acc = (f4v){0.f, 0.f, 0.f, 0.f};
    for (int j = off + g; j < off + cnt; j += 4) {
        int2 p = pairs[j];
        f4v bs = __builtin_nontemporal_load(
            (const f4v*)(basis + (size_t)p.x * DD + c4));
        f4v uu = *(const f4v*)(upd + (size_t)p.y * DD + c4);
        acc += bs * uu;
    }
    // fold the 4 triple-groups: butterfly over lane^16, lane^32
    acc.x += __shfl_xor(acc.x, 16, 64);
    acc.y += __shfl_xor(acc.y, 16, 64);
    acc.z += __shfl_xor(acc.z, 16, 64);
    acc.w += __shfl_xor(acc.w, 16, 64);
    acc.x += __shfl_xor(acc.x, 32, 64);
    acc.y += __shfl_xor(acc.y, 32, 64);
    acc.z += __shfl_xor(acc.z, 32, 64);
    acc.w += __shfl_xor(acc.w, 32, 64);

    if (g == 0) *(f4v*)(&sRow[wave * DD + c4]) = acc;
    __syncthreads();

    float sum = b[lane];
#pragma unroll
    for (int k = 0; k < DD; ++k)
        sum = fmaf(sRow[wave * DD + k], sW[k * DD + lane], sum);

    size_t o = (size_t)bnd * DD + lane;
    out[o] = bond[o] + sum;
}

// ---------------------------------------------------------------------------
// Fallback path (ws too small): atomic scatter
// ---------------------------------------------------------------------------
__global__ __launch_bounds__(256) void scatter_kernel(
    const float* __restrict__ basis, const float* __restrict__ upd,
    const int* __restrict__ tbi, const int* __restrict__ bai,
    float* __restrict__ summed)
{
    int t  = blockIdx.x * 16 + (threadIdx.x >> 4);
    int c0 = (threadIdx.x & 15) * 4;
    int dst = tbi[2 * t];
    int src = tbi[2 * t + 1];
    int a   = bai[2 * src + 1];
    const float4 bs = *reinterpret_cast<const float4*>(basis + (size_t)t * DD + c0);
    const float4 uu = *reinterpret_cast<const float4*>(upd   + (size_t)a * DD + c0);
    float* p = summed + (size_t)dst * DD + c0;
    atomicAdd(p + 0, bs.x * uu.x);
    atomicAdd(p + 1, bs.y * uu.y);
    atomicAdd(p + 2, bs.z * uu.z);
    atomicAdd(p + 3, bs.w * uu.w);
}

__global__ __launch_bounds__(256) void fuse_kernel(
    const float* __restrict__ bond, const float* __restrict__ W,
    const float* __restrict__ b, float* __restrict__ io)
{
    __shared__ float sW[DD * DD];
    __shared__ float sRow[4 * DD];
    for (int i = threadIdx.x; i < DD * DD; i += 256) sW[i] = W[i];
    size_t base = (size_t)blockIdx.x * (4 * DD);
    sRow[threadIdx.x] = io[base + threadIdx.x];
    __syncthreads();
    int local = threadIdx.x >> 6;
    int c     = threadIdx.x & 63;
    float sum = b[c];
#pragma unroll
    for (int k = 0; k < DD; ++k)
        sum = fmaf(sRow[local * DD + k], sW[k * DD + c], sum);
    io[base + threadIdx.x] = bond[base + threadIdx.x] + sum;
}

extern "C" void kernel_launch(void* const* d_in, const int* in_sizes, int n_in,
                              void* d_out, int out_size, void* d_ws, size_t ws_size,
                              hipStream_t stream) {
    const float* atom  = (const float*)d_in[0];
    const float* bond  = (const float*)d_in[1];
    const float* basis = (const float*)d_in[2];
    const int*   bai   = (const int*)d_in[3];
    const int*   tbi   = (const int*)d_in[4];
    const float* Wu    = (const float*)d_in[5];
    const float* bu    = (const float*)d_in[6];
    const float* Wf    = (const float*)d_in[7];
    const float* bf    = (const float*)d_in[8];

    float* out = (float*)d_out;
    char*  ws  = (char*)d_ws;

    float* upd     = (float*)(ws + O_UPD);
    int*   counts  = (int*)  (ws + O_CNT);
    int*   offsets = (int*)  (ws + O_OFF);
    int*   cursor  = (int*)  (ws + O_CUR);
    int*   bsum    = (int*)  (ws + O_BS);
    int2*  pairs   = (int2*) (ws + O_PAIRS);

    atom_update_kernel<<<N_ATOMS / 4, 256, 0, stream>>>(atom, Wu, bu, upd);

    if (ws_size >= WS_NEED) {
        hipMemsetAsync(counts, 0, (size_t)N_BONDS * sizeof(int), stream);
        count_kernel<<<(N_TRIPLES + 255) / 256, 256, 0, stream>>>(tbi, counts);
        scan_blocks_kernel<<<SCAN_NBLK, 256, 0, stream>>>(counts, offsets, bsum);
        scan_top_kernel<<<1, 256, 0, stream>>>(bsum);
        add_offsets_kernel<<<(N_BONDS + 255) / 256, 256, 0, stream>>>(offsets, bsum, cursor);
        fill_kernel<<<(N_TRIPLES + 255) / 256, 256, 0, stream>>>(tbi, bai, cursor, pairs);

        gather_fuse_kernel<<<N_BONDS / 4, 256, 0, stream>>>(
            basis, upd, pairs, offsets, counts, bond, Wf, bf, out);
    } else {
        hipMemsetAsync(out, 0, (size_t)N_BONDS * DD * sizeof(float), stream);
        scatter_kernel<<<N_TRIPLES / 16, 256, 0, stream>>>(basis, upd, tbi, bai, out);
        fuse_kernel<<<N_BONDS / 4, 256, 0, stream>>>(bond, Wf, bf, out);
    }
}

// Round 4
// 491.801 us; speedup vs baseline: 4.2600x; 1.4223x over previous
//
#include <hip/hip_runtime.h>
#include <math.h>

#define N_ATOMS   50000
#define N_BONDS   500000
#define N_TRIPLES 2000000
#define DD        64
#define RSZ       68   // padded LDS row (breaks 4-way bank conflict on row writes)

typedef float f4v __attribute__((ext_vector_type(4)));

// ---------------- workspace layout (bytes) ----------------
#define O_UPD   0u                          // 50000*64*4 = 12,800,000
#define O_CNT   12800000u                   // 500000*4 -> pad 2,000,128
#define O_OFF   (O_CNT + 2000128u)          // 500001 ints (incl. total) fits pad
#define O_CUR   (O_OFF + 2000128u)
#define O_BS    (O_CUR + 2000128u)
#define O_PAIRS (O_BS + 4096u)              // 2,000,000 * 8 = 16,000,000
#define WS_NEED ((size_t)O_PAIRS + (size_t)N_TRIPLES * 8u)

#define SCAN_ELEMS 2048
#define SCAN_NBLK  ((N_BONDS + SCAN_ELEMS - 1) / SCAN_ELEMS)   // 245

// ---------------------------------------------------------------------------
// A: upd[a,c] = sigmoid(atom[a,:] @ W_update[:,c] + b_update[c])
// 16 atoms/block, 4 atoms/wave: sW read amortized over 4 rows.
// ---------------------------------------------------------------------------
__global__ __launch_bounds__(256) void atom_update2_kernel(
    const float* __restrict__ atom, const float* __restrict__ W,
    const float* __restrict__ bb, float* __restrict__ out)
{
    __shared__ float sW[DD * DD];
    __shared__ float sRow[16 * RSZ];
    for (int i = threadIdx.x; i < DD * DD; i += 256) sW[i] = W[i];

    const int wave = threadIdx.x >> 6;
    const int lane = threadIdx.x & 63;
    const int g    = lane >> 4;
    const int c4   = (lane & 15) * 4;
    const int aBase = blockIdx.x * 16 + wave * 4;

    f4v r = *(const f4v*)(atom + (size_t)(aBase + g) * DD + c4);
    *(f4v*)&sRow[(wave * 4 + g) * RSZ + c4] = r;
    __syncthreads();

    float y0 = bb[lane], y1 = y0, y2 = y0, y3 = y0;
    const float* r0 = &sRow[(wave * 4 + 0) * RSZ];
    const float* r1 = &sRow[(wave * 4 + 1) * RSZ];
    const float* r2 = &sRow[(wave * 4 + 2) * RSZ];
    const float* r3 = &sRow[(wave * 4 + 3) * RSZ];
#pragma unroll
    for (int k = 0; k < DD; ++k) {
        float wk = sW[k * DD + lane];
        y0 = fmaf(r0[k], wk, y0);
        y1 = fmaf(r1[k], wk, y1);
        y2 = fmaf(r2[k], wk, y2);
        y3 = fmaf(r3[k], wk, y3);
    }
    size_t o = (size_t)aBase * DD + lane;
    out[o]          = 1.0f / (1.0f + __expf(-y0));
    out[o + DD]     = 1.0f / (1.0f + __expf(-y1));
    out[o + 2*DD]   = 1.0f / (1.0f + __expf(-y2));
    out[o + 3*DD]   = 1.0f / (1.0f + __expf(-y3));
}

// ---------------------------------------------------------------------------
// B1: counts[dst]++ per triple
// ---------------------------------------------------------------------------
__global__ __launch_bounds__(256) void count_kernel(
    const int* __restrict__ tbi, int* __restrict__ counts)
{
    int t = blockIdx.x * 256 + threadIdx.x;
    if (t < N_TRIPLES) atomicAdd(&counts[tbi[2 * t]], 1);
}

// ---------------------------------------------------------------------------
// B2a: per-block exclusive scan (2048 elems/block) + block sums
// ---------------------------------------------------------------------------
__global__ __launch_bounds__(256) void scan_blocks_kernel(
    const int* __restrict__ counts, int* __restrict__ offsets,
    int* __restrict__ blockSums)
{
    __shared__ int s[256];
    int base = blockIdx.x * SCAN_ELEMS + threadIdx.x * 8;
    int v[8];
    int tsum = 0;
#pragma unroll
    for (int i = 0; i < 8; ++i) {
        int idx = base + i;
        v[i] = (idx < N_BONDS) ? counts[idx] : 0;
        tsum += v[i];
    }
    s[threadIdx.x] = tsum;
    __syncthreads();
    for (int off = 1; off < 256; off <<= 1) {
        int x = 0;
        if (threadIdx.x >= off) x = s[threadIdx.x - off];
        __syncthreads();
        if (threadIdx.x >= off) s[threadIdx.x] += x;
        __syncthreads();
    }
    int excl = s[threadIdx.x] - tsum;
    if (threadIdx.x == 255) blockSums[blockIdx.x] = s[255];
    int run = excl;
#pragma unroll
    for (int i = 0; i < 8; ++i) {
        int idx = base + i;
        if (idx < N_BONDS) offsets[idx] = run;
        run += v[i];
    }
}

// ---------------------------------------------------------------------------
// B2b: exclusive scan of the 245 block sums
// ---------------------------------------------------------------------------
__global__ __launch_bounds__(256) void scan_top_kernel(int* __restrict__ blockSums)
{
    __shared__ int s[SCAN_NBLK];
    for (int i = threadIdx.x; i < SCAN_NBLK; i += 256) s[i] = blockSums[i];
    __syncthreads();
    if (threadIdx.x == 0) {
        int acc = 0;
        for (int i = 0; i < SCAN_NBLK; ++i) { int t = s[i]; s[i] = acc; acc += t; }
    }
    __syncthreads();
    for (int i = threadIdx.x; i < SCAN_NBLK; i += 256) blockSums[i] = s[i];
}

// ---------------------------------------------------------------------------
// B2c: offsets += scanned block sum; cursor = offsets; offsets[N_BONDS]=total
// ---------------------------------------------------------------------------
__global__ __launch_bounds__(256) void add_offsets_kernel(
    int* __restrict__ offsets, const int* __restrict__ blockSums,
    int* __restrict__ cursor)
{
    int i = blockIdx.x * 256 + threadIdx.x;
    if (i < N_BONDS) {
        int o = offsets[i] + blockSums[i / SCAN_ELEMS];
        offsets[i] = o;
        cursor[i]  = o;
    }
    if (i == 0) offsets[N_BONDS] = N_TRIPLES;
}

// ---------------------------------------------------------------------------
// B3: fill CSR pairs[slot] = (triple_idx, atom_idx)
// ---------------------------------------------------------------------------
__global__ __launch_bounds__(256) void fill_kernel(
    const int* __restrict__ tbi, const int* __restrict__ bai,
    int* __restrict__ cursor, int2* __restrict__ pairs)
{
    int t = blockIdx.x * 256 + threadIdx.x;
    if (t >= N_TRIPLES) return;
    int dst = tbi[2 * t];
    int src = tbi[2 * t + 1];
    int a   = bai[2 * src + 1];
    int slot = atomicAdd(&cursor[dst], 1);
    pairs[slot] = make_int2(t, a);
}

// ---------------------------------------------------------------------------
// D: gather + segment-sum + fused (@W_fuse + b_fuse + bond_features)
// 16 bonds/block, 4 bonds/wave, one 16-lane GROUP per bond (float4/lane =
// full 64 channels -> no cross-group fold). Epilogue amortizes each sW[k]
// read over the wave's 4 bonds: LDS ops 128/bond -> ~84/bond.
// ---------------------------------------------------------------------------
__global__ __launch_bounds__(256) void gather_fuse2_kernel(
    const float* __restrict__ basis, const float* __restrict__ upd,
    const int2* __restrict__ pairs, const int* __restrict__ offsets,
    const float* __restrict__ bond, const float* __restrict__ W,
    const float* __restrict__ bb, float* __restrict__ out)
{
    __shared__ float sW[DD * DD];
    __shared__ float sRow[16 * RSZ];
    for (int i = threadIdx.x; i < DD * DD; i += 256) sW[i] = W[i];

    const int wave = threadIdx.x >> 6;
    const int lane = threadIdx.x & 63;
    const int g    = lane >> 4;          // group -> bond within wave
    const int c4   = (lane & 15) * 4;    // channel base (float4)
    const int bBase = blockIdx.x * 16 + wave * 4;
    const int myB   = bBase + g;

    int og = offsets[myB];
    int eg = offsets[myB + 1];

    f4v acc = (f4v){0.f, 0.f, 0.f, 0.f};
    for (int j = og; j < eg; ++j) {
        int2 p = pairs[j];                           // 16 lanes same addr
        f4v bs = __builtin_nontemporal_load(
            (const f4v*)(basis + (size_t)p.x * DD + c4));
        f4v uu = *(const f4v*)(upd + (size_t)p.y * DD + c4);
        acc += bs * uu;
    }
    *(f4v*)&sRow[(wave * 4 + g) * RSZ + c4] = acc;   // full bond row per group

    __syncthreads();   // publishes sW (sRow is wave-local; waitcnt suffices)

    float y0 = bb[lane], y1 = y0, y2 = y0, y3 = y0;
    const float* r0 = &sRow[(wave * 4 + 0) * RSZ];
    const float* r1 = &sRow[(wave * 4 + 1) * RSZ];
    const float* r2 = &sRow[(wave * 4 + 2) * RSZ];
    const float* r3 = &sRow[(wave * 4 + 3) * RSZ];
#pragma unroll
    for (int k = 0; k < DD; ++k) {
        float wk = sW[k * DD + lane];   // one read, 4 FMAs
        y0 = fmaf(r0[k], wk, y0);
        y1 = fmaf(r1[k], wk, y1);
        y2 = fmaf(r2[k], wk, y2);
        y3 = fmaf(r3[k], wk, y3);
    }
    size_t o = (size_t)bBase * DD + lane;
    out[o]        = bond[o]        + y0;
    out[o + DD]   = bond[o + DD]   + y1;
    out[o + 2*DD] = bond[o + 2*DD] + y2;
    out[o + 3*DD] = bond[o + 3*DD] + y3;
}

// ---------------------------------------------------------------------------
// Fallback path (ws too small): atomic scatter + separate fuse
// ---------------------------------------------------------------------------
__global__ __launch_bounds__(256) void scatter_kernel(
    const float* __restrict__ basis, const float* __restrict__ upd,
    const int* __restrict__ tbi, const int* __restrict__ bai,
    float* __restrict__ summed)
{
    int t  = blockIdx.x * 16 + (threadIdx.x >> 4);
    int c0 = (threadIdx.x & 15) * 4;
    int dst = tbi[2 * t];
    int src = tbi[2 * t + 1];
    int a   = bai[2 * src + 1];
    const float4 bs = *reinterpret_cast<const float4*>(basis + (size_t)t * DD + c0);
    const float4 uu = *reinterpret_cast<const float4*>(upd   + (size_t)a * DD + c0);
    float* p = summed + (size_t)dst * DD + c0;
    atomicAdd(p + 0, bs.x * uu.x);
    atomicAdd(p + 1, bs.y * uu.y);
    atomicAdd(p + 2, bs.z * uu.z);
    atomicAdd(p + 3, bs.w * uu.w);
}

__global__ __launch_bounds__(256) void fuse_kernel(
    const float* __restrict__ bond, const float* __restrict__ W,
    const float* __restrict__ b, float* __restrict__ io)
{
    __shared__ float sW[DD * DD];
    __shared__ float sRow[4 * DD];
    for (int i = threadIdx.x; i < DD * DD; i += 256) sW[i] = W[i];
    size_t base = (size_t)blockIdx.x * (4 * DD);
    sRow[threadIdx.x] = io[base + threadIdx.x];
    __syncthreads();
    int local = threadIdx.x >> 6;
    int c     = threadIdx.x & 63;
    float sum = b[c];
#pragma unroll
    for (int k = 0; k < DD; ++k)
        sum = fmaf(sRow[local * DD + k], sW[k * DD + c], sum);
    io[base + threadIdx.x] = bond[base + threadIdx.x] + sum;
}

extern "C" void kernel_launch(void* const* d_in, const int* in_sizes, int n_in,
                              void* d_out, int out_size, void* d_ws, size_t ws_size,
                              hipStream_t stream) {
    const float* atom  = (const float*)d_in[0];
    const float* bond  = (const float*)d_in[1];
    const float* basis = (const float*)d_in[2];
    const int*   bai   = (const int*)d_in[3];
    const int*   tbi   = (const int*)d_in[4];
    const float* Wu    = (const float*)d_in[5];
    const float* bu    = (const float*)d_in[6];
    const float* Wf    = (const float*)d_in[7];
    const float* bf    = (const float*)d_in[8];

    float* out = (float*)d_out;
    char*  ws  = (char*)d_ws;

    float* upd     = (float*)(ws + O_UPD);
    int*   counts  = (int*)  (ws + O_CNT);
    int*   offsets = (int*)  (ws + O_OFF);
    int*   cursor  = (int*)  (ws + O_CUR);
    int*   bsum    = (int*)  (ws + O_BS);
    int2*  pairs   = (int2*) (ws + O_PAIRS);

    atom_update2_kernel<<<N_ATOMS / 16, 256, 0, stream>>>(atom, Wu, bu, upd);

    if (ws_size >= WS_NEED) {
        hipMemsetAsync(counts, 0, (size_t)N_BONDS * sizeof(int), stream);
        count_kernel<<<(N_TRIPLES + 255) / 256, 256, 0, stream>>>(tbi, counts);
        scan_blocks_kernel<<<SCAN_NBLK, 256, 0, stream>>>(counts, offsets, bsum);
        scan_top_kernel<<<1, 256, 0, stream>>>(bsum);
        add_offsets_kernel<<<(N_BONDS + 255) / 256, 256, 0, stream>>>(offsets, bsum, cursor);
        fill_kernel<<<(N_TRIPLES + 255) / 256, 256, 0, stream>>>(tbi, bai, cursor, pairs);

        gather_fuse2_kernel<<<N_BONDS / 16, 256, 0, stream>>>(
            basis, upd, pairs, offsets, bond, Wf, bf, out);
    } else {
        hipMemsetAsync(out, 0, (size_t)N_BONDS * DD * sizeof(float), stream);
        scatter_kernel<<<N_TRIPLES / 16, 256, 0, stream>>>(basis, upd, tbi, bai, out);
        fuse_kernel<<<N_BONDS / 4, 256, 0, stream>>>(bond, Wf, bf, out);
    }
}

// Round 6
// 443.055 us; speedup vs baseline: 4.7287x; 1.1100x over previous
//
#include <hip/hip_runtime.h>
#include <math.h>

#define N_ATOMS   50000
#define N_BONDS   500000
#define N_TRIPLES 2000000
#define DD        64
#define RSZ       68   // padded LDS row

typedef float f4v __attribute__((ext_vector_type(4)));
typedef int   i4v __attribute__((ext_vector_type(4)));

// ---------------- workspace layout (bytes) ----------------
#define O_UPD   0u                          // 50000*64*4 = 12,800,000
#define O_CNT   12800000u                   // 500000*4 -> pad 2,000,128
#define O_OFF   (O_CNT + 2000128u)          // 500001 ints fits pad
#define O_CUR   (O_OFF + 2000128u)
#define O_BS    (O_CUR + 2000128u)
#define O_PAIRS (O_BS + 4096u)              // 2,000,000 * 8 = 16,000,000
#define WS_NEED ((size_t)O_PAIRS + (size_t)N_TRIPLES * 8u)

#define SCAN_ELEMS 2048
#define SCAN_NBLK  ((N_BONDS + SCAN_ELEMS - 1) / SCAN_ELEMS)   // 245

// ---------------------------------------------------------------------------
// A: upd[a,c] = sigmoid(atom[a,:] @ W_update[:,c] + b_update[c])
// ---------------------------------------------------------------------------
__global__ __launch_bounds__(256) void atom_update2_kernel(
    const float* __restrict__ atom, const float* __restrict__ W,
    const float* __restrict__ bb, float* __restrict__ out)
{
    __shared__ float sW[DD * DD];
    __shared__ float sRow[16 * RSZ];
    for (int i = threadIdx.x; i < DD * DD; i += 256) sW[i] = W[i];

    const int wave = threadIdx.x >> 6;
    const int lane = threadIdx.x & 63;
    const int g    = lane >> 4;
    const int c4   = (lane & 15) * 4;
    const int aBase = blockIdx.x * 16 + wave * 4;

    f4v r = *(const f4v*)(atom + (size_t)(aBase + g) * DD + c4);
    *(f4v*)&sRow[(wave * 4 + g) * RSZ + c4] = r;
    __syncthreads();

    float y0 = bb[lane], y1 = y0, y2 = y0, y3 = y0;
    const float* r0 = &sRow[(wave * 4 + 0) * RSZ];
    const float* r1 = &sRow[(wave * 4 + 1) * RSZ];
    const float* r2 = &sRow[(wave * 4 + 2) * RSZ];
    const float* r3 = &sRow[(wave * 4 + 3) * RSZ];
#pragma unroll
    for (int k = 0; k < DD; ++k) {
        float wk = sW[k * DD + lane];
        y0 = fmaf(r0[k], wk, y0);
        y1 = fmaf(r1[k], wk, y1);
        y2 = fmaf(r2[k], wk, y2);
        y3 = fmaf(r3[k], wk, y3);
    }
    size_t o = (size_t)aBase * DD + lane;
    out[o]          = 1.0f / (1.0f + __expf(-y0));
    out[o + DD]     = 1.0f / (1.0f + __expf(-y1));
    out[o + 2*DD]   = 1.0f / (1.0f + __expf(-y2));
    out[o + 3*DD]   = 1.0f / (1.0f + __expf(-y3));
}

// ---------------------------------------------------------------------------
// B1: counts[dst]++ ; 2 triples/thread via i4v load of tbi
// ---------------------------------------------------------------------------
__global__ __launch_bounds__(256) void count2_kernel(
    const i4v* __restrict__ tbi4, int* __restrict__ counts)
{
    int i = blockIdx.x * 256 + threadIdx.x;
    if (i < N_TRIPLES / 2) {
        i4v v = __builtin_nontemporal_load(tbi4 + i);  // (dst0,src0,dst1,src1)
        atomicAdd(&counts[v.x], 1);
        atomicAdd(&counts[v.z], 1);
    }
}

// ---------------------------------------------------------------------------
// B2a: per-block exclusive scan (2048 elems/block) + block sums
// ---------------------------------------------------------------------------
__global__ __launch_bounds__(256) void scan_blocks_kernel(
    const int* __restrict__ counts, int* __restrict__ offsets,
    int* __restrict__ blockSums)
{
    __shared__ int s[256];
    int base = blockIdx.x * SCAN_ELEMS + threadIdx.x * 8;
    int v[8];
    int tsum = 0;
#pragma unroll
    for (int i = 0; i < 8; ++i) {
        int idx = base + i;
        v[i] = (idx < N_BONDS) ? counts[idx] : 0;
        tsum += v[i];
    }
    s[threadIdx.x] = tsum;
    __syncthreads();
    for (int off = 1; off < 256; off <<= 1) {
        int x = 0;
        if (threadIdx.x >= off) x = s[threadIdx.x - off];
        __syncthreads();
        if (threadIdx.x >= off) s[threadIdx.x] += x;
        __syncthreads();
    }
    int excl = s[threadIdx.x] - tsum;
    if (threadIdx.x == 255) blockSums[blockIdx.x] = s[255];
    int run = excl;
#pragma unroll
    for (int i = 0; i < 8; ++i) {
        int idx = base + i;
        if (idx < N_BONDS) offsets[idx] = run;
        run += v[i];
    }
}

// ---------------------------------------------------------------------------
// B2b: exclusive scan of the 245 block sums
// ---------------------------------------------------------------------------
__global__ __launch_bounds__(256) void scan_top_kernel(int* __restrict__ blockSums)
{
    __shared__ int s[SCAN_NBLK];
    for (int i = threadIdx.x; i < SCAN_NBLK; i += 256) s[i] = blockSums[i];
    __syncthreads();
    if (threadIdx.x == 0) {
        int acc = 0;
        for (int i = 0; i < SCAN_NBLK; ++i) { int t = s[i]; s[i] = acc; acc += t; }
    }
    __syncthreads();
    for (int i = threadIdx.x; i < SCAN_NBLK; i += 256) blockSums[i] = s[i];
}

// ---------------------------------------------------------------------------
// B2c: offsets += scanned block sum; cursor = offsets; offsets[N_BONDS]=total
// ---------------------------------------------------------------------------
__global__ __launch_bounds__(256) void add_offsets_kernel(
    int* __restrict__ offsets, const int* __restrict__ blockSums,
    int* __restrict__ cursor)
{
    int i = blockIdx.x * 256 + threadIdx.x;
    if (i < N_BONDS) {
        int o = offsets[i] + blockSums[i / SCAN_ELEMS];
        offsets[i] = o;
        cursor[i]  = o;
    }
    if (i == 0) offsets[N_BONDS] = N_TRIPLES;
}

// ---------------------------------------------------------------------------
// B3: fill CSR pairs[slot] = (triple_idx, atom_idx); 2 triples/thread
// ---------------------------------------------------------------------------
__global__ __launch_bounds__(256) void fill2_kernel(
    const i4v* __restrict__ tbi4, const int* __restrict__ bai,
    int* __restrict__ cursor, int2* __restrict__ pairs)
{
    int i = blockIdx.x * 256 + threadIdx.x;
    if (i >= N_TRIPLES / 2) return;
    i4v v = __builtin_nontemporal_load(tbi4 + i);  // (dst0,src0,dst1,src1)
    int a0 = bai[2 * v.y + 1];
    int a1 = bai[2 * v.w + 1];
    int s0 = atomicAdd(&cursor[v.x], 1);
    pairs[s0] = make_int2(2 * i, a0);
    int s1 = atomicAdd(&cursor[v.z], 1);
    pairs[s1] = make_int2(2 * i + 1, a1);
}

// ---------------------------------------------------------------------------
// D: gather + segment-sum + fused epilogue.
// Wave = 4 bonds. Cooperative pairs preload (1 coalesced load for the whole
// wave range) + flattened union loop: 4 slots/round over the 4-bond range
// (rounds = ceil(n/4) ~ 4.5 vs max-of-4-Poisson ~ 7.5), with per-segment
// predicated accumulators folded by a 2-step butterfly. Epilogue reads rows
// via ds_read_b128 broadcasts: 128 LDS instr/wave instead of 320.
// ---------------------------------------------------------------------------
__global__ __launch_bounds__(256) void gather_fuse3_kernel(
    const float* __restrict__ basis, const float* __restrict__ upd,
    const int2* __restrict__ pairs, const int* __restrict__ offsets,
    const float* __restrict__ bond, const float* __restrict__ W,
    const float* __restrict__ bb, float* __restrict__ out)
{
    __shared__ float sW[DD * DD];
    __shared__ float sRow[16 * RSZ];
    for (int i = threadIdx.x; i < DD * DD; i += 256) sW[i] = W[i];

    const int wave = threadIdx.x >> 6;
    const int lane = threadIdx.x & 63;
    const int g    = lane >> 4;          // group 0..3
    const int c4   = (lane & 15) * 4;    // channel quad
    const int bBase = blockIdx.x * 16 + wave * 4;

    // segment boundaries for the wave's 4 bonds
    int o0 = offsets[bBase];
    int o1 = offsets[bBase + 1];
    int o2 = offsets[bBase + 2];
    int o3 = offsets[bBase + 3];
    int o4 = offsets[bBase + 4];
    int n  = o4 - o0;

    // prefetch bond rows + bias early (hide the 128MB stream under the gather)
    size_t ob = (size_t)bBase * DD + lane;
    float bv0 = __builtin_nontemporal_load(bond + ob);
    float bv1 = __builtin_nontemporal_load(bond + ob + DD);
    float bv2 = __builtin_nontemporal_load(bond + ob + 2 * DD);
    float bv3 = __builtin_nontemporal_load(bond + ob + 3 * DD);
    float bias = bb[lane];

    // cooperative preload of up to 64 pairs (covers the whole wave range)
    int2 myp = make_int2(0, 0);
    if (lane < n) myp = pairs[o0 + lane];

    f4v acc0 = (f4v){0.f,0.f,0.f,0.f}, acc1 = acc0, acc2 = acc0, acc3 = acc0;
    const int rounds = (n + 3) >> 2;
    for (int r = 0; r < rounds; ++r) {
        int sIdx = r * 4 + g;
        bool valid = sIdx < n;
        int px = 0, py = 0;
        if (r < 16) {                       // wave-uniform branch
            px = __shfl(myp.x, sIdx, 64);
            py = __shfl(myp.y, sIdx, 64);
        } else if (valid) {                 // astronomically rare tail
            int2 pp = pairs[o0 + sIdx];
            px = pp.x; py = pp.y;
        }
        int s_abs = o0 + sIdx;
        int seg = (s_abs >= o1) + (s_abs >= o2) + (s_abs >= o3);
        f4v bs = (f4v){0.f,0.f,0.f,0.f};
        f4v uu = bs;
        if (valid) {
            bs = __builtin_nontemporal_load(
                (const f4v*)(basis + (size_t)px * DD + c4));
            uu = *(const f4v*)(upd + (size_t)py * DD + c4);
        }
        f4v prod = bs * uu;
        const f4v z = (f4v){0.f,0.f,0.f,0.f};
        acc0 += (seg == 0) ? prod : z;
        acc1 += (seg == 1) ? prod : z;
        acc2 += (seg == 2) ? prod : z;
        acc3 += (seg == 3) ? prod : z;
    }

    // fold across the 4 groups (bits 4,5 of lane)
#define FOLD4(A) \
    A.x += __shfl_xor(A.x, 16, 64); A.y += __shfl_xor(A.y, 16, 64); \
    A.z += __shfl_xor(A.z, 16, 64); A.w += __shfl_xor(A.w, 16, 64); \
    A.x += __shfl_xor(A.x, 32, 64); A.y += __shfl_xor(A.y, 32, 64); \
    A.z += __shfl_xor(A.z, 32, 64); A.w += __shfl_xor(A.w, 32, 64);
    FOLD4(acc0) FOLD4(acc1) FOLD4(acc2) FOLD4(acc3)
#undef FOLD4

    f4v mine = (g == 0) ? acc0 : (g == 1) ? acc1 : (g == 2) ? acc2 : acc3;
    *(f4v*)&sRow[(wave * 4 + g) * RSZ + c4] = mine;
    __syncthreads();

    float y0 = bias, y1 = bias, y2 = bias, y3 = bias;
    const float* r0 = &sRow[(wave * 4 + 0) * RSZ];
    const float* r1 = &sRow[(wave * 4 + 1) * RSZ];
    const float* r2 = &sRow[(wave * 4 + 2) * RSZ];
    const float* r3 = &sRow[(wave * 4 + 3) * RSZ];
#pragma unroll
    for (int k4 = 0; k4 < DD / 4; ++k4) {
        f4v a0 = *(const f4v*)&r0[k4 * 4];   // ds_read_b128 broadcast
        f4v a1 = *(const f4v*)&r1[k4 * 4];
        f4v a2 = *(const f4v*)&r2[k4 * 4];
        f4v a3 = *(const f4v*)&r3[k4 * 4];
#pragma unroll
        for (int kk = 0; kk < 4; ++kk) {
            float wk = sW[(k4 * 4 + kk) * DD + lane];
            y0 = fmaf(a0[kk], wk, y0);
            y1 = fmaf(a1[kk], wk, y1);
            y2 = fmaf(a2[kk], wk, y2);
            y3 = fmaf(a3[kk], wk, y3);
        }
    }
    __builtin_nontemporal_store(bv0 + y0, out + ob);
    __builtin_nontemporal_store(bv1 + y1, out + ob + DD);
    __builtin_nontemporal_store(bv2 + y2, out + ob + 2 * DD);
    __builtin_nontemporal_store(bv3 + y3, out + ob + 3 * DD);
}

// ---------------------------------------------------------------------------
// Fallback path (ws too small): atomic scatter + separate fuse
// ---------------------------------------------------------------------------
__global__ __launch_bounds__(256) void scatter_kernel(
    const float* __restrict__ basis, const float* __restrict__ upd,
    const int* __restrict__ tbi, const int* __restrict__ bai,
    float* __restrict__ summed)
{
    int t  = blockIdx.x * 16 + (threadIdx.x >> 4);
    int c0 = (threadIdx.x & 15) * 4;
    int dst = tbi[2 * t];
    int src = tbi[2 * t + 1];
    int a   = bai[2 * src + 1];
    const float4 bs = *reinterpret_cast<const float4*>(basis + (size_t)t * DD + c0);
    const float4 uu = *reinterpret_cast<const float4*>(upd   + (size_t)a * DD + c0);
    float* p = summed + (size_t)dst * DD + c0;
    atomicAdd(p + 0, bs.x * uu.x);
    atomicAdd(p + 1, bs.y * uu.y);
    atomicAdd(p + 2, bs.z * uu.z);
    atomicAdd(p + 3, bs.w * uu.w);
}

__global__ __launch_bounds__(256) void fuse_kernel(
    const float* __restrict__ bond, const float* __restrict__ W,
    const float* __restrict__ b, float* __restrict__ io)
{
    __shared__ float sW[DD * DD];
    __shared__ float sRow[4 * DD];
    for (int i = threadIdx.x; i < DD * DD; i += 256) sW[i] = W[i];
    size_t base = (size_t)blockIdx.x * (4 * DD);
    sRow[threadIdx.x] = io[base + threadIdx.x];
    __syncthreads();
    int local = threadIdx.x >> 6;
    int c     = threadIdx.x & 63;
    float sum = b[c];
#pragma unroll
    for (int k = 0; k < DD; ++k)
        sum = fmaf(sRow[local * DD + k], sW[k * DD + c], sum);
    io[base + threadIdx.x] = bond[base + threadIdx.x] + sum;
}

extern "C" void kernel_launch(void* const* d_in, const int* in_sizes, int n_in,
                              void* d_out, int out_size, void* d_ws, size_t ws_size,
                              hipStream_t stream) {
    const float* atom  = (const float*)d_in[0];
    const float* bond  = (const float*)d_in[1];
    const float* basis = (const float*)d_in[2];
    const int*   bai   = (const int*)d_in[3];
    const int*   tbi   = (const int*)d_in[4];
    const float* Wu    = (const float*)d_in[5];
    const float* bu    = (const float*)d_in[6];
    const float* Wf    = (const float*)d_in[7];
    const float* bf    = (const float*)d_in[8];

    float* out = (float*)d_out;
    char*  ws  = (char*)d_ws;

    float* upd     = (float*)(ws + O_UPD);
    int*   counts  = (int*)  (ws + O_CNT);
    int*   offsets = (int*)  (ws + O_OFF);
    int*   cursor  = (int*)  (ws + O_CUR);
    int*   bsum    = (int*)  (ws + O_BS);
    int2*  pairs   = (int2*) (ws + O_PAIRS);

    atom_update2_kernel<<<N_ATOMS / 16, 256, 0, stream>>>(atom, Wu, bu, upd);

    if (ws_size >= WS_NEED) {
        hipMemsetAsync(counts, 0, (size_t)N_BONDS * sizeof(int), stream);
        count2_kernel<<<(N_TRIPLES / 2 + 255) / 256, 256, 0, stream>>>(
            (const i4v*)tbi, counts);
        scan_blocks_kernel<<<SCAN_NBLK, 256, 0, stream>>>(counts, offsets, bsum);
        scan_top_kernel<<<1, 256, 0, stream>>>(bsum);
        add_offsets_kernel<<<(N_BONDS + 255) / 256, 256, 0, stream>>>(offsets, bsum, cursor);
        fill2_kernel<<<(N_TRIPLES / 2 + 255) / 256, 256, 0, stream>>>(
            (const i4v*)tbi, bai, cursor, pairs);

        gather_fuse3_kernel<<<N_BONDS / 16, 256, 0, stream>>>(
            basis, upd, pairs, offsets, bond, Wf, bf, out);
    } else {
        hipMemsetAsync(out, 0, (size_t)N_BONDS * DD * sizeof(float), stream);
        scatter_kernel<<<N_TRIPLES / 16, 256, 0, stream>>>(basis, upd, tbi, bai, out);
        fuse_kernel<<<N_BONDS / 4, 256, 0, stream>>>(bond, Wf, bf, out);
    }
}

// Round 7
// 438.739 us; speedup vs baseline: 4.7752x; 1.0098x over previous
//
#include <hip/hip_runtime.h>
#include <math.h>

#define N_ATOMS   50000
#define N_BONDS   500000
#define N_TRIPLES 2000000
#define DD        64
#define RSZ       68   // padded LDS row

typedef float f4v __attribute__((ext_vector_type(4)));
typedef int   i4v __attribute__((ext_vector_type(4)));

// ---------------- workspace layout (bytes) ----------------
#define O_UPD   0u                          // 50000*64*4 = 12,800,000
#define O_CNT   12800000u                   // 500000*4 -> pad 2,000,128
#define O_OFF   (O_CNT + 2000128u)          // 500001 ints fits pad
#define O_CUR   (O_OFF + 2000128u)
#define O_BS    (O_CUR + 2000128u)
#define O_PAIRS (O_BS + 4096u)              // 2,000,000 * 8 = 16,000,000
#define WS_NEED ((size_t)O_PAIRS + (size_t)N_TRIPLES * 8u)

#define SCAN_ELEMS 2048
#define SCAN_NBLK  ((N_BONDS + SCAN_ELEMS - 1) / SCAN_ELEMS)   // 245

// ---------------------------------------------------------------------------
// A: upd[a,c] = sigmoid(atom[a,:] @ W_update[:,c] + b_update[c])
// Also zeroes counts[] (160 ints per block x 3125 blocks = 500000),
// replacing the hipMemsetAsync graph node.
// ---------------------------------------------------------------------------
__global__ __launch_bounds__(256) void atom_update3_kernel(
    const float* __restrict__ atom, const float* __restrict__ W,
    const float* __restrict__ bb, float* __restrict__ out,
    int* __restrict__ counts)
{
    // zero my slice of counts (independent of the matmul below)
    if (threadIdx.x < 160) counts[blockIdx.x * 160 + threadIdx.x] = 0;

    __shared__ float sW[DD * DD];
    __shared__ float sRow[16 * RSZ];
    for (int i = threadIdx.x; i < DD * DD; i += 256) sW[i] = W[i];

    const int wave = threadIdx.x >> 6;
    const int lane = threadIdx.x & 63;
    const int g    = lane >> 4;
    const int c4   = (lane & 15) * 4;
    const int aBase = blockIdx.x * 16 + wave * 4;

    f4v r = *(const f4v*)(atom + (size_t)(aBase + g) * DD + c4);
    *(f4v*)&sRow[(wave * 4 + g) * RSZ + c4] = r;
    __syncthreads();

    float y0 = bb[lane], y1 = y0, y2 = y0, y3 = y0;
    const float* r0 = &sRow[(wave * 4 + 0) * RSZ];
    const float* r1 = &sRow[(wave * 4 + 1) * RSZ];
    const float* r2 = &sRow[(wave * 4 + 2) * RSZ];
    const float* r3 = &sRow[(wave * 4 + 3) * RSZ];
#pragma unroll
    for (int k = 0; k < DD; ++k) {
        float wk = sW[k * DD + lane];
        y0 = fmaf(r0[k], wk, y0);
        y1 = fmaf(r1[k], wk, y1);
        y2 = fmaf(r2[k], wk, y2);
        y3 = fmaf(r3[k], wk, y3);
    }
    size_t o = (size_t)aBase * DD + lane;
    out[o]          = 1.0f / (1.0f + __expf(-y0));
    out[o + DD]     = 1.0f / (1.0f + __expf(-y1));
    out[o + 2*DD]   = 1.0f / (1.0f + __expf(-y2));
    out[o + 3*DD]   = 1.0f / (1.0f + __expf(-y3));
}

// ---------------------------------------------------------------------------
// B1: counts[dst]++ ; 2 triples/thread via i4v load of tbi
// ---------------------------------------------------------------------------
__global__ __launch_bounds__(256) void count2_kernel(
    const i4v* __restrict__ tbi4, int* __restrict__ counts)
{
    int i = blockIdx.x * 256 + threadIdx.x;
    if (i < N_TRIPLES / 2) {
        i4v v = __builtin_nontemporal_load(tbi4 + i);  // (dst0,src0,dst1,src1)
        atomicAdd(&counts[v.x], 1);
        atomicAdd(&counts[v.z], 1);
    }
}

// ---------------------------------------------------------------------------
// B2a: per-block exclusive scan (2048 elems/block) + raw block sums
// ---------------------------------------------------------------------------
__global__ __launch_bounds__(256) void scan_blocks_kernel(
    const int* __restrict__ counts, int* __restrict__ offsets,
    int* __restrict__ blockSums)
{
    __shared__ int s[256];
    int base = blockIdx.x * SCAN_ELEMS + threadIdx.x * 8;
    int v[8];
    int tsum = 0;
#pragma unroll
    for (int i = 0; i < 8; ++i) {
        int idx = base + i;
        v[i] = (idx < N_BONDS) ? counts[idx] : 0;
        tsum += v[i];
    }
    s[threadIdx.x] = tsum;
    __syncthreads();
    for (int off = 1; off < 256; off <<= 1) {
        int x = 0;
        if (threadIdx.x >= off) x = s[threadIdx.x - off];
        __syncthreads();
        if (threadIdx.x >= off) s[threadIdx.x] += x;
        __syncthreads();
    }
    int excl = s[threadIdx.x] - tsum;
    if (threadIdx.x == 255) blockSums[blockIdx.x] = s[255];
    int run = excl;
#pragma unroll
    for (int i = 0; i < 8; ++i) {
        int idx = base + i;
        if (idx < N_BONDS) offsets[idx] = run;
        run += v[i];
    }
}

// ---------------------------------------------------------------------------
// B2b: add block prefix (computed in-block by a redundant 245-elem LDS scan,
// replacing the separate scan_top kernel); cursor = offsets; sentinel at end.
// Each 256-bond chunk lies in exactly one 2048-elem scan region.
// ---------------------------------------------------------------------------
__global__ __launch_bounds__(256) void add_offsets2_kernel(
    int* __restrict__ offsets, const int* __restrict__ blockSums,
    int* __restrict__ cursor)
{
    __shared__ int s[256];
    const int t = threadIdx.x;
    int v = (t < SCAN_NBLK) ? blockSums[t] : 0;
    s[t] = v;
    __syncthreads();
    for (int off = 1; off < 256; off <<= 1) {
        int x = 0;
        if (t >= off) x = s[t - off];
        __syncthreads();
        if (t >= off) s[t] += x;
        __syncthreads();
    }
    const int R = blockIdx.x >> 3;                 // region of this block
    int pref = s[R] - blockSums[R];                // exclusive prefix of R

    int i = blockIdx.x * 256 + t;
    if (i < N_BONDS) {
        int o = offsets[i] + pref;
        offsets[i] = o;
        cursor[i]  = o;
    }
    if (i == 0) offsets[N_BONDS] = N_TRIPLES;
}

// ---------------------------------------------------------------------------
// B3: fill CSR pairs[slot] = (triple_idx, atom_idx); 2 triples/thread
// ---------------------------------------------------------------------------
__global__ __launch_bounds__(256) void fill2_kernel(
    const i4v* __restrict__ tbi4, const int* __restrict__ bai,
    int* __restrict__ cursor, int2* __restrict__ pairs)
{
    int i = blockIdx.x * 256 + threadIdx.x;
    if (i >= N_TRIPLES / 2) return;
    i4v v = __builtin_nontemporal_load(tbi4 + i);  // (dst0,src0,dst1,src1)
    int a0 = bai[2 * v.y + 1];
    int a1 = bai[2 * v.w + 1];
    int s0 = atomicAdd(&cursor[v.x], 1);
    pairs[s0] = make_int2(2 * i, a0);
    int s1 = atomicAdd(&cursor[v.z], 1);
    pairs[s1] = make_int2(2 * i + 1, a1);
}

// ---------------------------------------------------------------------------
// D: gather + segment-sum + fused epilogue.
// Wave = 4 bonds, flattened union loop at 8 slots/round (2 per 16-lane
// group): each thread has up to 4 independent 16B loads in flight per
// round -> half the latency-serialized rounds of round 6. Per-slot validity
// is group-uniform, so invalid slots issue no loads (zero wasted fetch).
// ---------------------------------------------------------------------------
__global__ __launch_bounds__(256) void gather_fuse4_kernel(
    const float* __restrict__ basis, const float* __restrict__ upd,
    const int2* __restrict__ pairs, const int* __restrict__ offsets,
    const float* __restrict__ bond, const float* __restrict__ W,
    const float* __restrict__ bb, float* __restrict__ out)
{
    __shared__ float sW[DD * DD];
    __shared__ float sRow[16 * RSZ];
    for (int i = threadIdx.x; i < DD * DD; i += 256) sW[i] = W[i];

    const int wave = threadIdx.x >> 6;
    const int lane = threadIdx.x & 63;
    const int g    = lane >> 4;          // group 0..3
    const int c4   = (lane & 15) * 4;    // channel quad
    const int bBase = blockIdx.x * 16 + wave * 4;

    int o0 = offsets[bBase];
    int o1 = offsets[bBase + 1];
    int o2 = offsets[bBase + 2];
    int o3 = offsets[bBase + 3];
    int o4 = offsets[bBase + 4];
    int n  = o4 - o0;

    // prefetch bond rows + bias early
    size_t ob = (size_t)bBase * DD + lane;
    float bv0 = __builtin_nontemporal_load(bond + ob);
    float bv1 = __builtin_nontemporal_load(bond + ob + DD);
    float bv2 = __builtin_nontemporal_load(bond + ob + 2 * DD);
    float bv3 = __builtin_nontemporal_load(bond + ob + 3 * DD);
    float bias = bb[lane];

    // cooperative preload of up to 64 pairs
    int2 myp = make_int2(0, 0);
    if (lane < n) myp = pairs[o0 + lane];

    f4v acc0 = (f4v){0.f,0.f,0.f,0.f}, acc1 = acc0, acc2 = acc0, acc3 = acc0;
    const f4v z = (f4v){0.f,0.f,0.f,0.f};
    const int rounds = (n + 7) >> 3;
    for (int r = 0; r < rounds; ++r) {
        int sA = r * 8 + g;          // slot for this group, sub-round A
        int sB = sA + 4;             // sub-round B
        bool vA = sA < n, vB = sB < n;

        int pxA = __shfl(myp.x, sA & 63, 64);
        int pyA = __shfl(myp.y, sA & 63, 64);
        int pxB = __shfl(myp.x, sB & 63, 64);
        int pyB = __shfl(myp.y, sB & 63, 64);
        if (sA >= 64 && vA) { int2 t = pairs[o0 + sA]; pxA = t.x; pyA = t.y; }
        if (sB >= 64 && vB) { int2 t = pairs[o0 + sB]; pxB = t.x; pyB = t.y; }

        int aA = o0 + sA, aB = o0 + sB;
        int segA = (aA >= o1) + (aA >= o2) + (aA >= o3);
        int segB = (aB >= o1) + (aB >= o2) + (aB >= o3);

        f4v bsA = z, uuA = z, bsB = z, uuB = z;
        if (vA) {
            bsA = __builtin_nontemporal_load(
                (const f4v*)(basis + (size_t)pxA * DD + c4));
            uuA = *(const f4v*)(upd + (size_t)pyA * DD + c4);
        }
        if (vB) {
            bsB = __builtin_nontemporal_load(
                (const f4v*)(basis + (size_t)pxB * DD + c4));
            uuB = *(const f4v*)(upd + (size_t)pyB * DD + c4);
        }
        f4v pA = bsA * uuA;
        f4v pB = bsB * uuB;
        acc0 += ((segA == 0) ? pA : z) + ((segB == 0) ? pB : z);
        acc1 += ((segA == 1) ? pA : z) + ((segB == 1) ? pB : z);
        acc2 += ((segA == 2) ? pA : z) + ((segB == 2) ? pB : z);
        acc3 += ((segA == 3) ? pA : z) + ((segB == 3) ? pB : z);
    }

    // fold across the 4 groups (bits 4,5 of lane)
#define FOLD4(A) \
    A.x += __shfl_xor(A.x, 16, 64); A.y += __shfl_xor(A.y, 16, 64); \
    A.z += __shfl_xor(A.z, 16, 64); A.w += __shfl_xor(A.w, 16, 64); \
    A.x += __shfl_xor(A.x, 32, 64); A.y += __shfl_xor(A.y, 32, 64); \
    A.z += __shfl_xor(A.z, 32, 64); A.w += __shfl_xor(A.w, 32, 64);
    FOLD4(acc0) FOLD4(acc1) FOLD4(acc2) FOLD4(acc3)
#undef FOLD4

    f4v mine = (g == 0) ? acc0 : (g == 1) ? acc1 : (g == 2) ? acc2 : acc3;
    *(f4v*)&sRow[(wave * 4 + g) * RSZ + c4] = mine;
    __syncthreads();

    float y0 = bias, y1 = bias, y2 = bias, y3 = bias;
    const float* r0 = &sRow[(wave * 4 + 0) * RSZ];
    const float* r1 = &sRow[(wave * 4 + 1) * RSZ];
    const float* r2 = &sRow[(wave * 4 + 2) * RSZ];
    const float* r3 = &sRow[(wave * 4 + 3) * RSZ];
#pragma unroll
    for (int k4 = 0; k4 < DD / 4; ++k4) {
        f4v a0 = *(const f4v*)&r0[k4 * 4];   // ds_read_b128 broadcast
        f4v a1 = *(const f4v*)&r1[k4 * 4];
        f4v a2 = *(const f4v*)&r2[k4 * 4];
        f4v a3 = *(const f4v*)&r3[k4 * 4];
#pragma unroll
        for (int kk = 0; kk < 4; ++kk) {
            float wk = sW[(k4 * 4 + kk) * DD + lane];
            y0 = fmaf(a0[kk], wk, y0);
            y1 = fmaf(a1[kk], wk, y1);
            y2 = fmaf(a2[kk], wk, y2);
            y3 = fmaf(a3[kk], wk, y3);
        }
    }
    __builtin_nontemporal_store(bv0 + y0, out + ob);
    __builtin_nontemporal_store(bv1 + y1, out + ob + DD);
    __builtin_nontemporal_store(bv2 + y2, out + ob + 2 * DD);
    __builtin_nontemporal_store(bv3 + y3, out + ob + 3 * DD);
}

// ---------------------------------------------------------------------------
// Fallback path (ws too small): atomic scatter + separate fuse
// ---------------------------------------------------------------------------
__global__ __launch_bounds__(256) void scatter_kernel(
    const float* __restrict__ basis, const float* __restrict__ upd,
    const int* __restrict__ tbi, const int* __restrict__ bai,
    float* __restrict__ summed)
{
    int t  = blockIdx.x * 16 + (threadIdx.x >> 4);
    int c0 = (threadIdx.x & 15) * 4;
    int dst = tbi[2 * t];
    int src = tbi[2 * t + 1];
    int a   = bai[2 * src + 1];
    const float4 bs = *reinterpret_cast<const float4*>(basis + (size_t)t * DD + c0);
    const float4 uu = *reinterpret_cast<const float4*>(upd   + (size_t)a * DD + c0);
    float* p = summed + (size_t)dst * DD + c0;
    atomicAdd(p + 0, bs.x * uu.x);
    atomicAdd(p + 1, bs.y * uu.y);
    atomicAdd(p + 2, bs.z * uu.z);
    atomicAdd(p + 3, bs.w * uu.w);
}

__global__ __launch_bounds__(256) void fuse_kernel(
    const float* __restrict__ bond, const float* __restrict__ W,
    const float* __restrict__ b, float* __restrict__ io)
{
    __shared__ float sW[DD * DD];
    __shared__ float sRow[4 * DD];
    for (int i = threadIdx.x; i < DD * DD; i += 256) sW[i] = W[i];
    size_t base = (size_t)blockIdx.x * (4 * DD);
    sRow[threadIdx.x] = io[base + threadIdx.x];
    __syncthreads();
    int local = threadIdx.x >> 6;
    int c     = threadIdx.x & 63;
    float sum = b[c];
#pragma unroll
    for (int k = 0; k < DD; ++k)
        sum = fmaf(sRow[local * DD + k], sW[k * DD + c], sum);
    io[base + threadIdx.x] = bond[base + threadIdx.x] + sum;
}

extern "C" void kernel_launch(void* const* d_in, const int* in_sizes, int n_in,
                              void* d_out, int out_size, void* d_ws, size_t ws_size,
                              hipStream_t stream) {
    const float* atom  = (const float*)d_in[0];
    const float* bond  = (const float*)d_in[1];
    const float* basis = (const float*)d_in[2];
    const int*   bai   = (const int*)d_in[3];
    const int*   tbi   = (const int*)d_in[4];
    const float* Wu    = (const float*)d_in[5];
    const float* bu    = (const float*)d_in[6];
    const float* Wf    = (const float*)d_in[7];
    const float* bf    = (const float*)d_in[8];

    float* out = (float*)d_out;
    char*  ws  = (char*)d_ws;

    float* upd     = (float*)(ws + O_UPD);
    int*   counts  = (int*)  (ws + O_CNT);
    int*   offsets = (int*)  (ws + O_OFF);
    int*   cursor  = (int*)  (ws + O_CUR);
    int*   bsum    = (int*)  (ws + O_BS);
    int2*  pairs   = (int2*) (ws + O_PAIRS);

    if (ws_size >= WS_NEED) {
        // atom update + counts zeroing fused (no memset node)
        atom_update3_kernel<<<N_ATOMS / 16, 256, 0, stream>>>(atom, Wu, bu, upd, counts);
        count2_kernel<<<(N_TRIPLES / 2 + 255) / 256, 256, 0, stream>>>(
            (const i4v*)tbi, counts);
        scan_blocks_kernel<<<SCAN_NBLK, 256, 0, stream>>>(counts, offsets, bsum);
        add_offsets2_kernel<<<(N_BONDS + 255) / 256, 256, 0, stream>>>(offsets, bsum, cursor);
        fill2_kernel<<<(N_TRIPLES / 2 + 255) / 256, 256, 0, stream>>>(
            (const i4v*)tbi, bai, cursor, pairs);
        gather_fuse4_kernel<<<N_BONDS / 16, 256, 0, stream>>>(
            basis, upd, pairs, offsets, bond, Wf, bf, out);
    } else {
        atom_update3_kernel<<<N_ATOMS / 16, 256, 0, stream>>>(atom, Wu, bu, upd, counts);
        hipMemsetAsync(out, 0, (size_t)N_BONDS * DD * sizeof(float), stream);
        scatter_kernel<<<N_TRIPLES / 16, 256, 0, stream>>>(basis, upd, tbi, bai, out);
        fuse_kernel<<<N_BONDS / 4, 256, 0, stream>>>(bond, Wf, bf, out);
    }
}

// Round 8
// 364.561 us; speedup vs baseline: 5.7469x; 1.2035x over previous
//
#include <hip/hip_runtime.h>
#include <math.h>

#define N_ATOMS   50000
#define N_BONDS   500000
#define N_TRIPLES 2000000
#define DD        64
#define RSZ       68   // padded LDS row
#define CAP       16   // bucket capacity per bond (Poisson(4); P(X>16)~4e-6)

typedef float f4v __attribute__((ext_vector_type(4)));
typedef int   i4v __attribute__((ext_vector_type(4)));

// ---------------- workspace layout (bytes) ----------------
#define O_UPD   0u                            // 50000*64*4 = 12,800,000
#define O_CUR   12800000u                     // 500000*4 -> pad 2,000,128
#define O_BKT   (O_CUR + 2000128u)            // 500000*16*8 = 64,000,000
#define O_OVFC  (O_BKT + 64000000u)           // 128 B (overflow counter)
#define O_OVF   (O_OVFC + 128u)               // 2M*12 = 24,000,000 (full capacity)
#define WS_NEED ((size_t)O_OVF + 24000000u)

// ---------------------------------------------------------------------------
// A: upd[a,c] = sigmoid(atom[a,:] @ W_update[:,c] + b_update[c])
// Also zeroes cursor[] (160 ints/block x 3125 blocks) and the overflow ctr.
// ---------------------------------------------------------------------------
__global__ __launch_bounds__(256) void atom_update3_kernel(
    const float* __restrict__ atom, const float* __restrict__ W,
    const float* __restrict__ bb, float* __restrict__ out,
    int* __restrict__ cursor, int* __restrict__ ovf_cnt)
{
    if (cursor != nullptr && threadIdx.x < 160)
        cursor[blockIdx.x * 160 + threadIdx.x] = 0;
    if (ovf_cnt != nullptr && blockIdx.x == 0 && threadIdx.x == 0)
        *ovf_cnt = 0;

    __shared__ float sW[DD * DD];
    __shared__ float sRow[16 * RSZ];
    for (int i = threadIdx.x; i < DD * DD; i += 256) sW[i] = W[i];

    const int wave = threadIdx.x >> 6;
    const int lane = threadIdx.x & 63;
    const int g    = lane >> 4;
    const int c4   = (lane & 15) * 4;
    const int aBase = blockIdx.x * 16 + wave * 4;

    f4v r = *(const f4v*)(atom + (size_t)(aBase + g) * DD + c4);
    *(f4v*)&sRow[(wave * 4 + g) * RSZ + c4] = r;
    __syncthreads();

    float y0 = bb[lane], y1 = y0, y2 = y0, y3 = y0;
    const float* r0 = &sRow[(wave * 4 + 0) * RSZ];
    const float* r1 = &sRow[(wave * 4 + 1) * RSZ];
    const float* r2 = &sRow[(wave * 4 + 2) * RSZ];
    const float* r3 = &sRow[(wave * 4 + 3) * RSZ];
#pragma unroll
    for (int k = 0; k < DD; ++k) {
        float wk = sW[k * DD + lane];
        y0 = fmaf(r0[k], wk, y0);
        y1 = fmaf(r1[k], wk, y1);
        y2 = fmaf(r2[k], wk, y2);
        y3 = fmaf(r3[k], wk, y3);
    }
    size_t o = (size_t)aBase * DD + lane;
    out[o]          = 1.0f / (1.0f + __expf(-y0));
    out[o + DD]     = 1.0f / (1.0f + __expf(-y1));
    out[o + 2*DD]   = 1.0f / (1.0f + __expf(-y2));
    out[o + 3*DD]   = 1.0f / (1.0f + __expf(-y3));
}

// ---------------------------------------------------------------------------
// B: direct bucket fill — one pass, no count/scan.
// pairs[dst*CAP + slot] = (triple, atom); slot via atomicAdd(cursor[dst]).
// Overflow (slot >= CAP, ~never) goes to a full-capacity list.
// ---------------------------------------------------------------------------
__global__ __launch_bounds__(256) void fill_bucket_kernel(
    const i4v* __restrict__ tbi4, const int* __restrict__ bai,
    int* __restrict__ cursor, int2* __restrict__ pairs,
    int* __restrict__ ovf_cnt, int* __restrict__ ovf)
{
    int i = blockIdx.x * 256 + threadIdx.x;
    if (i >= N_TRIPLES / 2) return;
    i4v v = __builtin_nontemporal_load(tbi4 + i);  // (dst0,src0,dst1,src1)
    int a0 = bai[2 * v.y + 1];
    int a1 = bai[2 * v.w + 1];

    int s0 = atomicAdd(&cursor[v.x], 1);
    if (s0 < CAP) {
        pairs[(size_t)v.x * CAP + s0] = make_int2(2 * i, a0);
    } else {
        int o = atomicAdd(ovf_cnt, 1);
        ovf[3 * o] = v.x; ovf[3 * o + 1] = 2 * i; ovf[3 * o + 2] = a0;
    }
    int s1 = atomicAdd(&cursor[v.z], 1);
    if (s1 < CAP) {
        pairs[(size_t)v.z * CAP + s1] = make_int2(2 * i + 1, a1);
    } else {
        int o = atomicAdd(ovf_cnt, 1);
        ovf[3 * o] = v.z; ovf[3 * o + 1] = 2 * i + 1; ovf[3 * o + 2] = a1;
    }
}

// ---------------------------------------------------------------------------
// C: gather + segment-sum + fused (@W_fuse + b_fuse + bond_features).
// Wave = 4 bonds, 16-lane group per bond. Lane l preloads bucket slot
// (l&15) of its group's bond in one coalesced 512B wave load. 4 slots per
// round (4 independent 256B basis loads in flight per thread), all into
// ONE accumulator per group -> no segmented accs, no butterfly folds.
// ---------------------------------------------------------------------------
__global__ __launch_bounds__(256) void gather_fuse5_kernel(
    const float* __restrict__ basis, const float* __restrict__ upd,
    const int2* __restrict__ pairs, const int* __restrict__ cnts,
    const int* __restrict__ ovf_cnt, const int* __restrict__ ovf,
    const float* __restrict__ bond, const float* __restrict__ W,
    const float* __restrict__ bb, float* __restrict__ out)
{
    __shared__ float sW[DD * DD];
    __shared__ float sRow[16 * RSZ];
    for (int i = threadIdx.x; i < DD * DD; i += 256) sW[i] = W[i];

    const int wave = threadIdx.x >> 6;
    const int lane = threadIdx.x & 63;
    const int g    = lane >> 4;          // group -> bond within wave
    const int c4   = (lane & 15) * 4;    // channel quad
    const int bBase = blockIdx.x * 16 + wave * 4;
    const int myB   = bBase + g;

    int cntRaw = cnts[myB];
    int cnt    = min(cntRaw, CAP);
    // wave-max count for the loop bound
    int wm = cnt;
    wm = max(wm, __shfl_xor(wm, 16, 64));
    wm = max(wm, __shfl_xor(wm, 32, 64));

    // prefetch bond rows + bias early
    size_t ob = (size_t)bBase * DD + lane;
    float bv0 = __builtin_nontemporal_load(bond + ob);
    float bv1 = __builtin_nontemporal_load(bond + ob + DD);
    float bv2 = __builtin_nontemporal_load(bond + ob + 2 * DD);
    float bv3 = __builtin_nontemporal_load(bond + ob + 3 * DD);
    float bias = bb[lane];

    // coalesced preload: lane l holds slot (l&15) of its group's bucket
    int2 myp = pairs[(size_t)myB * CAP + (lane & 15)];

    const f4v z = (f4v){0.f,0.f,0.f,0.f};
    f4v acc = z;
    for (int r = 0; r * 4 < wm; ++r) {
#pragma unroll
        for (int i = 0; i < 4; ++i) {
            int s  = r * 4 + i;
            int px = __shfl(myp.x, g * 16 + s, 64);
            int py = __shfl(myp.y, g * 16 + s, 64);
            if (s < cnt) {
                f4v bs = __builtin_nontemporal_load(
                    (const f4v*)(basis + (size_t)px * DD + c4));
                f4v uu = *(const f4v*)(upd + (size_t)py * DD + c4);
                acc += bs * uu;
            }
        }
    }

    // overflow replay (novf == 0 essentially always)
    int novf = *ovf_cnt;
    if (novf > 0) {
        for (int i = 0; i < novf; ++i) {
            int dst = ovf[3 * i];
            if (dst == myB) {
                int t = ovf[3 * i + 1], a = ovf[3 * i + 2];
                f4v bs = *(const f4v*)(basis + (size_t)t * DD + c4);
                f4v uu = *(const f4v*)(upd + (size_t)a * DD + c4);
                acc += bs * uu;
            }
        }
    }

    *(f4v*)&sRow[(wave * 4 + g) * RSZ + c4] = acc;
    __syncthreads();

    float y0 = bias, y1 = bias, y2 = bias, y3 = bias;
    const float* r0 = &sRow[(wave * 4 + 0) * RSZ];
    const float* r1 = &sRow[(wave * 4 + 1) * RSZ];
    const float* r2 = &sRow[(wave * 4 + 2) * RSZ];
    const float* r3 = &sRow[(wave * 4 + 3) * RSZ];
#pragma unroll
    for (int k4 = 0; k4 < DD / 4; ++k4) {
        f4v a0 = *(const f4v*)&r0[k4 * 4];   // ds_read_b128 broadcast
        f4v a1 = *(const f4v*)&r1[k4 * 4];
        f4v a2 = *(const f4v*)&r2[k4 * 4];
        f4v a3 = *(const f4v*)&r3[k4 * 4];
#pragma unroll
        for (int kk = 0; kk < 4; ++kk) {
            float wk = sW[(k4 * 4 + kk) * DD + lane];
            y0 = fmaf(a0[kk], wk, y0);
            y1 = fmaf(a1[kk], wk, y1);
            y2 = fmaf(a2[kk], wk, y2);
            y3 = fmaf(a3[kk], wk, y3);
        }
    }
    __builtin_nontemporal_store(bv0 + y0, out + ob);
    __builtin_nontemporal_store(bv1 + y1, out + ob + DD);
    __builtin_nontemporal_store(bv2 + y2, out + ob + 2 * DD);
    __builtin_nontemporal_store(bv3 + y3, out + ob + 3 * DD);
}

// ---------------------------------------------------------------------------
// Fallback path (ws too small): atomic scatter + separate fuse
// ---------------------------------------------------------------------------
__global__ __launch_bounds__(256) void scatter_kernel(
    const float* __restrict__ basis, const float* __restrict__ upd,
    const int* __restrict__ tbi, const int* __restrict__ bai,
    float* __restrict__ summed)
{
    int t  = blockIdx.x * 16 + (threadIdx.x >> 4);
    int c0 = (threadIdx.x & 15) * 4;
    int dst = tbi[2 * t];
    int src = tbi[2 * t + 1];
    int a   = bai[2 * src + 1];
    const float4 bs = *reinterpret_cast<const float4*>(basis + (size_t)t * DD + c0);
    const float4 uu = *reinterpret_cast<const float4*>(upd   + (size_t)a * DD + c0);
    float* p = summed + (size_t)dst * DD + c0;
    atomicAdd(p + 0, bs.x * uu.x);
    atomicAdd(p + 1, bs.y * uu.y);
    atomicAdd(p + 2, bs.z * uu.z);
    atomicAdd(p + 3, bs.w * uu.w);
}

__global__ __launch_bounds__(256) void fuse_kernel(
    const float* __restrict__ bond, const float* __restrict__ W,
    const float* __restrict__ b, float* __restrict__ io)
{
    __shared__ float sW[DD * DD];
    __shared__ float sRow[4 * DD];
    for (int i = threadIdx.x; i < DD * DD; i += 256) sW[i] = W[i];
    size_t base = (size_t)blockIdx.x * (4 * DD);
    sRow[threadIdx.x] = io[base + threadIdx.x];
    __syncthreads();
    int local = threadIdx.x >> 6;
    int c     = threadIdx.x & 63;
    float sum = b[c];
#pragma unroll
    for (int k = 0; k < DD; ++k)
        sum = fmaf(sRow[local * DD + k], sW[k * DD + c], sum);
    io[base + threadIdx.x] = bond[base + threadIdx.x] + sum;
}

extern "C" void kernel_launch(void* const* d_in, const int* in_sizes, int n_in,
                              void* d_out, int out_size, void* d_ws, size_t ws_size,
                              hipStream_t stream) {
    const float* atom  = (const float*)d_in[0];
    const float* bond  = (const float*)d_in[1];
    const float* basis = (const float*)d_in[2];
    const int*   bai   = (const int*)d_in[3];
    const int*   tbi   = (const int*)d_in[4];
    const float* Wu    = (const float*)d_in[5];
    const float* bu    = (const float*)d_in[6];
    const float* Wf    = (const float*)d_in[7];
    const float* bf    = (const float*)d_in[8];

    float* out = (float*)d_out;
    char*  ws  = (char*)d_ws;

    float* upd     = (float*)(ws + O_UPD);
    int*   cursor  = (int*)  (ws + O_CUR);
    int2*  pairs   = (int2*) (ws + O_BKT);
    int*   ovf_cnt = (int*)  (ws + O_OVFC);
    int*   ovf     = (int*)  (ws + O_OVF);

    if (ws_size >= WS_NEED) {
        atom_update3_kernel<<<N_ATOMS / 16, 256, 0, stream>>>(
            atom, Wu, bu, upd, cursor, ovf_cnt);
        fill_bucket_kernel<<<(N_TRIPLES / 2 + 255) / 256, 256, 0, stream>>>(
            (const i4v*)tbi, bai, cursor, pairs, ovf_cnt, ovf);
        gather_fuse5_kernel<<<N_BONDS / 16, 256, 0, stream>>>(
            basis, upd, pairs, cursor, ovf_cnt, ovf, bond, Wf, bf, out);
    } else {
        atom_update3_kernel<<<N_ATOMS / 16, 256, 0, stream>>>(
            atom, Wu, bu, upd, nullptr, nullptr);
        hipMemsetAsync(out, 0, (size_t)N_BONDS * DD * sizeof(float), stream);
        scatter_kernel<<<N_TRIPLES / 16, 256, 0, stream>>>(basis, upd, tbi, bai, out);
        fuse_kernel<<<N_BONDS / 4, 256, 0, stream>>>(bond, Wf, bf, out);
    }
}